// Round 4
// baseline (572.351 us; speedup 1.0000x reference)
//
#include <hip/hip_runtime.h>

#define T_TOK 4096
#define H_DIM 512
#define I_DIM 1024
#define E_NUM 32
#define KTOP  2
#define CAP   512
#define NROWS (E_NUM * CAP)    // 16384
#define NPAIR (T_TOK * KTOP)   // 8192

typedef __attribute__((ext_vector_type(8))) short short8;    // 8 bf16 = 4 VGPRs
typedef __attribute__((ext_vector_type(4))) float float4v;
typedef __attribute__((ext_vector_type(4))) unsigned int uint4v;

// round-half-up bf16 (differs from RNE only on exact ties; inputs finite)
__device__ __forceinline__ unsigned int pack_rn(float a, float b) {
  unsigned int ua = __float_as_uint(a) + 0x8000u;
  unsigned int ub = __float_as_uint(b) + 0x8000u;
  return (ua >> 16) | (ub & 0xffff0000u);
}
__device__ __forceinline__ unsigned short f2bf_rn(float f) {
  return (unsigned short)((__float_as_uint(f) + 0x8000u) >> 16);
}
__device__ __forceinline__ float bf2f(unsigned short s) {
  return __uint_as_float(((unsigned int)s) << 16);
}
__device__ __forceinline__ uint4v cvt8u(float4v f0, float4v f1) {
  uint4v u;
  u.x = pack_rn(f0.x, f0.y);
  u.y = pack_rn(f0.z, f0.w);
  u.z = pack_rn(f1.x, f1.y);
  u.w = pack_rn(f1.z, f1.w);
  return u;
}

// ---------------- routing ----------------
__global__ void k_route(const int* __restrict__ idx, int* __restrict__ counts,
                        int* __restrict__ slot_token, int* __restrict__ inv) {
  int i = blockIdx.x * 256 + threadIdx.x;
  if (i >= NPAIR) return;
  int e = idx[i];
  int p = atomicAdd(counts + e, 1);
  if (p < CAP) {
    slot_token[e * CAP + p] = i >> 1;  // KTOP == 2
    inv[i] = e * CAP + p;
  } else {
    inv[i] = -1;
  }
}

// ---------------- gather tokens -> bf16 dispatch buffer (zero-pad to 32 rows) ----
__global__ void k_gather(const float* __restrict__ hs, const int* __restrict__ counts,
                         const int* __restrict__ slot_token, unsigned short* __restrict__ xd) {
  const int r = blockIdx.x * 4 + (threadIdx.x >> 6);  // one wave per row
  const int lane = threadIdx.x & 63;
  const int e = r >> 9;
  const int p = r & (CAP - 1);
  const int cnt = min(counts[e], CAP);
  if (p >= ((cnt + 31) & ~31)) return;  // beyond last 32-row tile: never read
  uint4v v = {0u, 0u, 0u, 0u};
  if (p < cnt) {
    const int t = slot_token[r];
    const float4v* src = (const float4v*)(hs + (size_t)t * H_DIM);
    float4v f0 = src[lane * 2];
    float4v f1 = src[lane * 2 + 1];
    v = cvt8u(f0, f1);
  }
  *(uint4v*)(xd + (size_t)r * H_DIM + lane * 8) = v;
}

// ---------------- GEMM1, weight-stationary ----------------
// Block = (expert e, 32 gate cols + matching 32 up cols). Stage BOTH weight slices'
// full K=512 depth into LDS once (fp32->bf16, 64 KB), then barrier-free compute:
// each of 8 waves owns 32-row tiles, B from LDS, A via 16B bf16 global loads.
// LDS chunk layout: [tile][kc*32 + (col ^ (kc&7))] of 16B; swizzle makes both the
// staged writes and the frag reads conflict-free.
__global__ __launch_bounds__(512, 4) void k_gemm1(const unsigned short* __restrict__ xd,
                                                  const float* __restrict__ gup,
                                                  const int* __restrict__ counts,
                                                  unsigned short* __restrict__ act) {
  __shared__ unsigned short ldsb[2 * 2048 * 8];  // 64 KB

  const int e = blockIdx.y;
  const int c0 = blockIdx.x * 32;
  const int tid = threadIdx.x;

  const float* wbase = gup + (size_t)e * (2 * I_DIM * H_DIM);
#pragma unroll
  for (int q = 0; q < 8; ++q) {
    int c = q * 512 + tid;
    int tile = c >> 11;       // 0 = gate, 1 = up
    int r = c & 2047;
    int col = r >> 6;         // 0..31
    int kc = r & 63;          // 8-float chunk along K
    const float* g = wbase + (size_t)(tile * I_DIM + c0 + col) * H_DIM + kc * 8;
    float4v f0 = *(const float4v*)g;
    float4v f1 = *(const float4v*)(g + 4);
    int idx = tile * 2048 + kc * 32 + (col ^ (kc & 7));
    *(uint4v*)(ldsb + (size_t)idx * 8) = cvt8u(f0, f1);
  }
  __syncthreads();

  const int cnt = min(counts[e], CAP);
  const int ntiles = (cnt + 31) >> 5;
  const int w = tid >> 6;
  const int lane = tid & 63;
  const int ml = lane & 15, kg = lane >> 4;

  for (int rt = w; rt < ntiles; rt += 8) {
    const unsigned short* ap = xd + (size_t)(e * CAP + rt * 32 + ml) * H_DIM + kg * 8;

    float4v accg[2][2] = {};
    float4v accu[2][2] = {};
    short8 aC[2], bgC[2], buC[2], aN[2], bgN[2], buN[2];

    {  // k-step 0 frags
      aC[0] = *(const short8*)(ap);
      aC[1] = *(const short8*)(ap + 16 * H_DIM);
      int kchunk = kg;
      int sw = kchunk & 7;
      bgC[0] = *(const short8*)(ldsb + (size_t)(kchunk * 32 + (ml ^ sw)) * 8);
      bgC[1] = *(const short8*)(ldsb + (size_t)(kchunk * 32 + 16 + (ml ^ sw)) * 8);
      buC[0] = *(const short8*)(ldsb + (size_t)(2048 + kchunk * 32 + (ml ^ sw)) * 8);
      buC[1] = *(const short8*)(ldsb + (size_t)(2048 + kchunk * 32 + 16 + (ml ^ sw)) * 8);
    }

    for (int kk = 0; kk < H_DIM; kk += 32) {
      const int kn = kk + 32;
      if (kn < H_DIM) {  // 1-step pipeline: prefetch next while MFMA on current
        aN[0] = *(const short8*)(ap + kn);
        aN[1] = *(const short8*)(ap + 16 * H_DIM + kn);
        int kchunk = (kn >> 3) + kg;
        int sw = kchunk & 7;
        bgN[0] = *(const short8*)(ldsb + (size_t)(kchunk * 32 + (ml ^ sw)) * 8);
        bgN[1] = *(const short8*)(ldsb + (size_t)(kchunk * 32 + 16 + (ml ^ sw)) * 8);
        buN[0] = *(const short8*)(ldsb + (size_t)(2048 + kchunk * 32 + (ml ^ sw)) * 8);
        buN[1] = *(const short8*)(ldsb + (size_t)(2048 + kchunk * 32 + 16 + (ml ^ sw)) * 8);
      }
#pragma unroll
      for (int mi = 0; mi < 2; ++mi)
#pragma unroll
        for (int ni = 0; ni < 2; ++ni) {
          accg[mi][ni] = __builtin_amdgcn_mfma_f32_16x16x32_bf16(aC[mi], bgC[ni], accg[mi][ni], 0, 0, 0);
          accu[mi][ni] = __builtin_amdgcn_mfma_f32_16x16x32_bf16(aC[mi], buC[ni], accu[mi][ni], 0, 0, 0);
        }
      aC[0] = aN[0]; aC[1] = aN[1];
      bgC[0] = bgN[0]; bgC[1] = bgN[1];
      buC[0] = buN[0]; buC[1] = buN[1];
    }

    unsigned short* ao = act + (size_t)(e * CAP + rt * 32) * I_DIM + c0;
#pragma unroll
    for (int mi = 0; mi < 2; ++mi)
#pragma unroll
      for (int rg = 0; rg < 4; ++rg) {
        int row = mi * 16 + kg * 4 + rg;
#pragma unroll
        for (int ni = 0; ni < 2; ++ni) {
          float g = accg[mi][ni][rg];
          float u = accu[mi][ni][rg];
          float a = (g / (1.0f + __expf(-g))) * u;
          ao[(size_t)row * I_DIM + ni * 16 + ml] = f2bf_rn(a);
        }
      }
  }
}

// ---------------- GEMM2, weight-stationary: act x down^T -> yd bf16 ----------------
__global__ __launch_bounds__(512, 4) void k_gemm2(const unsigned short* __restrict__ act,
                                                  const float* __restrict__ dwn,
                                                  const int* __restrict__ counts,
                                                  unsigned short* __restrict__ yd) {
  __shared__ unsigned short ldsb[4096 * 8];  // 64 KB: 32 cols x K=1024

  const int e = blockIdx.y;
  const int c0 = blockIdx.x * 32;
  const int tid = threadIdx.x;

  const float* wbase = dwn + (size_t)e * (H_DIM * I_DIM);
#pragma unroll
  for (int q = 0; q < 8; ++q) {
    int c = q * 512 + tid;
    int col = c >> 7;         // 0..31
    int kc = c & 127;         // 8-float chunk along K=1024
    const float* g = wbase + (size_t)(c0 + col) * I_DIM + kc * 8;
    float4v f0 = *(const float4v*)g;
    float4v f1 = *(const float4v*)(g + 4);
    int idx = kc * 32 + (col ^ (kc & 7));
    *(uint4v*)(ldsb + (size_t)idx * 8) = cvt8u(f0, f1);
  }
  __syncthreads();

  const int cnt = min(counts[e], CAP);
  const int ntiles = (cnt + 31) >> 5;
  const int w = tid >> 6;
  const int lane = tid & 63;
  const int ml = lane & 15, kg = lane >> 4;

  for (int rt = w; rt < ntiles; rt += 8) {
    const unsigned short* ap = act + (size_t)(e * CAP + rt * 32 + ml) * I_DIM + kg * 8;

    float4v acc[2][2] = {};
    short8 aC[2], bC[2], aN[2], bN[2];

    {
      aC[0] = *(const short8*)(ap);
      aC[1] = *(const short8*)(ap + 16 * I_DIM);
      int kchunk = kg;
      int sw = kchunk & 7;
      bC[0] = *(const short8*)(ldsb + (size_t)(kchunk * 32 + (ml ^ sw)) * 8);
      bC[1] = *(const short8*)(ldsb + (size_t)(kchunk * 32 + 16 + (ml ^ sw)) * 8);
    }

    for (int kk = 0; kk < I_DIM; kk += 32) {
      const int kn = kk + 32;
      if (kn < I_DIM) {
        aN[0] = *(const short8*)(ap + kn);
        aN[1] = *(const short8*)(ap + 16 * I_DIM + kn);
        int kchunk = (kn >> 3) + kg;
        int sw = kchunk & 7;
        bN[0] = *(const short8*)(ldsb + (size_t)(kchunk * 32 + (ml ^ sw)) * 8);
        bN[1] = *(const short8*)(ldsb + (size_t)(kchunk * 32 + 16 + (ml ^ sw)) * 8);
      }
#pragma unroll
      for (int mi = 0; mi < 2; ++mi)
#pragma unroll
        for (int ni = 0; ni < 2; ++ni)
          acc[mi][ni] = __builtin_amdgcn_mfma_f32_16x16x32_bf16(aC[mi], bC[ni], acc[mi][ni], 0, 0, 0);
      aC[0] = aN[0]; aC[1] = aN[1];
      bC[0] = bN[0]; bC[1] = bN[1];
    }

    unsigned short* yo = yd + (size_t)(e * CAP + rt * 32) * H_DIM + c0;
#pragma unroll
    for (int mi = 0; mi < 2; ++mi)
#pragma unroll
      for (int rg = 0; rg < 4; ++rg) {
        int row = mi * 16 + kg * 4 + rg;
#pragma unroll
        for (int ni = 0; ni < 2; ++ni)
          yo[(size_t)row * H_DIM + ni * 16 + ml] = f2bf_rn(acc[mi][ni][rg]);
      }
  }
}

// ---------------- combine: out[t] = sum_k w[t,k] * yd[inv[t,k]] ----------------
__global__ void k_combine(const unsigned short* __restrict__ yd, const int* __restrict__ inv,
                          const float* __restrict__ wts, float* __restrict__ out) {
  const int t = blockIdx.x * 4 + (threadIdx.x >> 6);  // one wave per token
  const int lane = threadIdx.x & 63;
  const int i0 = 2 * t, i1 = 2 * t + 1;
  const int r0 = inv[i0], r1 = inv[i1];
  float o[8] = {0.f, 0.f, 0.f, 0.f, 0.f, 0.f, 0.f, 0.f};
  if (r0 >= 0) {
    float w = wts[i0];
    short8 y = *(const short8*)(yd + (size_t)r0 * H_DIM + lane * 8);
#pragma unroll
    for (int j = 0; j < 8; ++j) o[j] += w * bf2f((unsigned short)y[j]);
  }
  if (r1 >= 0) {
    float w = wts[i1];
    short8 y = *(const short8*)(yd + (size_t)r1 * H_DIM + lane * 8);
#pragma unroll
    for (int j = 0; j < 8; ++j) o[j] += w * bf2f((unsigned short)y[j]);
  }
  float4v v0 = {o[0], o[1], o[2], o[3]};
  float4v v1 = {o[4], o[5], o[6], o[7]};
  float4v* dst = (float4v*)(out + (size_t)t * H_DIM + lane * 8);
  dst[0] = v0;
  dst[1] = v1;
}

extern "C" void kernel_launch(void* const* d_in, const int* in_sizes, int n_in,
                              void* d_out, int out_size, void* d_ws, size_t ws_size,
                              hipStream_t stream) {
  const float* hs  = (const float*)d_in[0];  // [T,H]
  const int*   idx = (const int*)d_in[1];    // [T,K]
  const float* wts = (const float*)d_in[2];  // [T,K]
  const float* gup = (const float*)d_in[3];  // [E,2I,H]
  const float* dwn = (const float*)d_in[4];  // [E,H,I]
  float* out = (float*)d_out;                // [T,H]

  char* ws = (char*)d_ws;
  int* counts       = (int*)ws;                             // 128 B used
  int* inv          = (int*)(ws + 1024);                    // 32 KB
  int* slot_token   = (int*)(ws + 1024 + 32768);            // 64 KB
  unsigned short* xd  = (unsigned short*)(ws + 131072);     // 16 MB
  unsigned short* act = xd + (size_t)NROWS * H_DIM;         // 32 MB
  unsigned short* yd  = xd;  // xd dead after gemm1; alias (16 MB)

  hipMemsetAsync(counts, 0, E_NUM * sizeof(int), stream);
  k_route<<<NPAIR / 256, 256, 0, stream>>>(idx, counts, slot_token, inv);
  k_gather<<<NROWS / 4, 256, 0, stream>>>(hs, counts, slot_token, xd);
  dim3 g1(I_DIM / 32, E_NUM);   // 32 x 32 = 1024 blocks
  k_gemm1<<<g1, 512, 0, stream>>>(xd, gup, counts, act);
  dim3 g2(H_DIM / 32, E_NUM);   // 16 x 32 = 512 blocks
  k_gemm2<<<g2, 512, 0, stream>>>(act, dwn, counts, yd);
  k_combine<<<T_TOK / 4, 256, 0, stream>>>(yd, inv, wts, out);
}

// Round 5
// 392.651 us; speedup vs baseline: 1.4577x; 1.4577x over previous
//
#include <hip/hip_runtime.h>

#define T_TOK 4096
#define H_DIM 512
#define I_DIM 1024
#define E_NUM 32
#define KTOP  2
#define CAP   512
#define NROWS (E_NUM * CAP)    // 16384
#define NPAIR (T_TOK * KTOP)   // 8192

typedef __attribute__((ext_vector_type(8))) short short8;    // 8 bf16 = 4 VGPRs
typedef __attribute__((ext_vector_type(4))) float float4v;
typedef __attribute__((ext_vector_type(4))) unsigned int uint4v;

// round-half-up bf16 (differs from RNE only on exact ties; inputs finite)
__device__ __forceinline__ unsigned int pack_rn(float a, float b) {
  unsigned int ua = __float_as_uint(a) + 0x8000u;
  unsigned int ub = __float_as_uint(b) + 0x8000u;
  return (ua >> 16) | (ub & 0xffff0000u);
}
__device__ __forceinline__ unsigned short f2bf_rn(float f) {
  return (unsigned short)((__float_as_uint(f) + 0x8000u) >> 16);
}
__device__ __forceinline__ float bf2f(unsigned short s) {
  return __uint_as_float(((unsigned int)s) << 16);
}
__device__ __forceinline__ uint4v cvt8u(float4v f0, float4v f1) {
  uint4v u;
  u.x = pack_rn(f0.x, f0.y);
  u.y = pack_rn(f0.z, f0.w);
  u.z = pack_rn(f1.x, f1.y);
  u.w = pack_rn(f1.z, f1.w);
  return u;
}

#define GLOAD_LDS16(gptr, lptr)                                                         \
  __builtin_amdgcn_global_load_lds((const __attribute__((address_space(1))) unsigned int*)(gptr), \
                                   (__attribute__((address_space(3))) unsigned int*)(lptr), 16, 0, 0)

// B-tile LDS swizzle: chunk (kc 0..3, n 0..63) -> chunk index. Writes (4 consecutive n x
// kc 0..3 per 16-lane phase) and reads (16 consecutive n, fixed kc) are both <=2-way. [R2: 0 conflicts]
#define SWZ64(kc, n) (((kc) << 6) | ((n) ^ ((kc) << 1)))

// ---------------- routing ----------------
__global__ void k_route(const int* __restrict__ idx, int* __restrict__ counts,
                        int* __restrict__ slot_token, int* __restrict__ inv) {
  int i = blockIdx.x * 256 + threadIdx.x;
  if (i >= NPAIR) return;
  int e = idx[i];
  int p = atomicAdd(counts + e, 1);
  if (p < CAP) {
    slot_token[e * CAP + p] = i >> 1;  // KTOP == 2
    inv[i] = e * CAP + p;
  } else {
    inv[i] = -1;
  }
}

// ---------------- gather tokens -> bf16 dispatch buffer (zero-pad to 64-row grain) ----
__global__ void k_gather(const float* __restrict__ hs, const int* __restrict__ counts,
                         const int* __restrict__ slot_token, unsigned short* __restrict__ xd) {
  const int r = blockIdx.x * 4 + (threadIdx.x >> 6);  // one wave per row
  const int lane = threadIdx.x & 63;
  const int e = r >> 9;
  const int p = r & (CAP - 1);
  const int cnt = min(counts[e], CAP);
  if (p >= ((cnt + 63) & ~63)) return;  // beyond last 64-row tile: never read
  uint4v v = {0u, 0u, 0u, 0u};
  if (p < cnt) {
    const int t = slot_token[r];
    const float4v* src = (const float4v*)(hs + (size_t)t * H_DIM);
    float4v f0 = src[lane * 2];
    float4v f1 = src[lane * 2 + 1];
    v = cvt8u(f0, f1);
  }
  *(uint4v*)(xd + (size_t)r * H_DIM + lane * 8) = v;
}

// ---------------- GEMM1: 64x(64g+64u) tiles, 2 waves, each wave 64x32g + 64x32u ----
// R2 k-plane LDS + DMA A + swizzled B staging, but 4x smaller acc footprint per wave
// (64 AGPR) -> 3-4 waves/SIMD, and 2x more active blocks -> latency hidden by TLP.
// Gate+up cols in the SAME wave -> silu fuse is register-local.
__global__ __launch_bounds__(128, 3) void k_gemm1(const unsigned short* __restrict__ xd,
                                                  const float* __restrict__ gup,
                                                  const int* __restrict__ counts,
                                                  unsigned short* __restrict__ act) {
  __shared__ unsigned short lA[256 * 8];   // [kc 0..3][row 0..63], 4 KB
  __shared__ unsigned short lBg[256 * 8];  // [kc][col^swz], 4 KB
  __shared__ unsigned short lBu[256 * 8];  // 4 KB

  const int r0 = blockIdx.y * 64;
  const int e = r0 >> 9;
  const int cnt = min(counts[e], CAP);
  if ((r0 & (CAP - 1)) >= cnt) return;

  const int tid = threadIdx.x;
  const int lane = tid & 63;
  const int w = tid >> 6;            // 0..1
  const int ml = lane & 15, kg = lane >> 4;
  const int c0 = blockIdx.x * 64;    // gate col base; up uses same offsets

  const float* bg_base = gup + (size_t)e * (2 * I_DIM * H_DIM) + (size_t)c0 * H_DIM;
  const float* bu_base = bg_base + (size_t)I_DIM * H_DIM;

  float4v accg[4][2] = {};
  float4v accu[4][2] = {};

  for (int kk = 0; kk < H_DIM; kk += 32) {
    // A: 256 16B chunks via DMA; wave w, pass q covers plane kc = 2q + w, rows = lanes
#pragma unroll
    for (int q = 0; q < 2; ++q) {
      const int kcA = 2 * q + w;
      const unsigned short* g = xd + (size_t)(r0 + lane) * H_DIM + kk + kcA * 8;
      unsigned short* l = lA + (size_t)(q * 128 + w * 64) * 8;  // wave-uniform base
      GLOAD_LDS16(g, l);
    }
    // B gate+up: fp32 -> bf16, swizzled writes (4 threads/col read 64B contiguous)
#pragma unroll
    for (int q = 0; q < 2; ++q) {
      int c = q * 128 + tid;
      int n = c >> 2, kc = c & 3;
      int dst = SWZ64(kc, n) * 8;
      {
        const float* g = bg_base + (size_t)n * H_DIM + kk + kc * 8;
        float4v f0 = *(const float4v*)g;
        float4v f1 = *(const float4v*)(g + 4);
        *(uint4v*)(lBg + dst) = cvt8u(f0, f1);
      }
      {
        const float* g = bu_base + (size_t)n * H_DIM + kk + kc * 8;
        float4v f0 = *(const float4v*)g;
        float4v f1 = *(const float4v*)(g + 4);
        *(uint4v*)(lBu + dst) = cvt8u(f0, f1);
      }
    }
    __syncthreads();

    short8 af[4], bgf[2], buf_[2];
#pragma unroll
    for (int mi = 0; mi < 4; ++mi)
      af[mi] = *(const short8*)(lA + (size_t)(kg * 64 + mi * 16 + ml) * 8);
#pragma unroll
    for (int ni = 0; ni < 2; ++ni) {
      int idx = (kg << 6) | ((w * 32 + ni * 16 + ml) ^ (kg << 1));
      bgf[ni] = *(const short8*)(lBg + (size_t)idx * 8);
      buf_[ni] = *(const short8*)(lBu + (size_t)idx * 8);
    }
#pragma unroll
    for (int mi = 0; mi < 4; ++mi)
#pragma unroll
      for (int ni = 0; ni < 2; ++ni) {
        accg[mi][ni] = __builtin_amdgcn_mfma_f32_16x16x32_bf16(af[mi], bgf[ni], accg[mi][ni], 0, 0, 0);
        accu[mi][ni] = __builtin_amdgcn_mfma_f32_16x16x32_bf16(af[mi], buf_[ni], accu[mi][ni], 0, 0, 0);
      }
    __syncthreads();
  }

  // epilogue: act = silu(g)*u (register-local), bf16
  unsigned short* ao = act + (size_t)r0 * I_DIM + c0 + w * 32;
#pragma unroll
  for (int mi = 0; mi < 4; ++mi)
#pragma unroll
    for (int rg = 0; rg < 4; ++rg) {
      int row = mi * 16 + kg * 4 + rg;
#pragma unroll
      for (int ni = 0; ni < 2; ++ni) {
        float g = accg[mi][ni][rg];
        float u = accu[mi][ni][rg];
        float a = (g / (1.0f + __expf(-g))) * u;
        ao[(size_t)row * I_DIM + ni * 16 + ml] = f2bf_rn(a);
      }
    }
}

// ---------------- GEMM2: 64x64 tiles, 2 waves, each wave 64x32; K=1024 ----
__global__ __launch_bounds__(128, 4) void k_gemm2(const unsigned short* __restrict__ act,
                                                  const float* __restrict__ dwn,
                                                  const int* __restrict__ counts,
                                                  unsigned short* __restrict__ yd) {
  __shared__ unsigned short lA[256 * 8];
  __shared__ unsigned short lB[256 * 8];

  const int r0 = blockIdx.y * 64;
  const int e = r0 >> 9;
  const int cnt = min(counts[e], CAP);
  if ((r0 & (CAP - 1)) >= cnt) return;

  const int tid = threadIdx.x;
  const int lane = tid & 63;
  const int w = tid >> 6;
  const int ml = lane & 15, kg = lane >> 4;
  const int c0 = blockIdx.x * 64;

  const float* b_base = dwn + (size_t)e * (H_DIM * I_DIM) + (size_t)c0 * I_DIM;

  float4v acc[4][2] = {};

  for (int kk = 0; kk < I_DIM; kk += 32) {
#pragma unroll
    for (int q = 0; q < 2; ++q) {
      const int kcA = 2 * q + w;
      const unsigned short* g = act + (size_t)(r0 + lane) * I_DIM + kk + kcA * 8;
      unsigned short* l = lA + (size_t)(q * 128 + w * 64) * 8;
      GLOAD_LDS16(g, l);
    }
#pragma unroll
    for (int q = 0; q < 2; ++q) {
      int c = q * 128 + tid;
      int n = c >> 2, kc = c & 3;
      const float* g = b_base + (size_t)n * I_DIM + kk + kc * 8;
      float4v f0 = *(const float4v*)g;
      float4v f1 = *(const float4v*)(g + 4);
      *(uint4v*)(lB + (size_t)(SWZ64(kc, n)) * 8) = cvt8u(f0, f1);
    }
    __syncthreads();

    short8 af[4], bf[2];
#pragma unroll
    for (int mi = 0; mi < 4; ++mi)
      af[mi] = *(const short8*)(lA + (size_t)(kg * 64 + mi * 16 + ml) * 8);
#pragma unroll
    for (int ni = 0; ni < 2; ++ni) {
      int idx = (kg << 6) | ((w * 32 + ni * 16 + ml) ^ (kg << 1));
      bf[ni] = *(const short8*)(lB + (size_t)idx * 8);
    }
#pragma unroll
    for (int mi = 0; mi < 4; ++mi)
#pragma unroll
      for (int ni = 0; ni < 2; ++ni)
        acc[mi][ni] = __builtin_amdgcn_mfma_f32_16x16x32_bf16(af[mi], bf[ni], acc[mi][ni], 0, 0, 0);
    __syncthreads();
  }

  unsigned short* yo = yd + (size_t)r0 * H_DIM + c0 + w * 32;
#pragma unroll
  for (int mi = 0; mi < 4; ++mi)
#pragma unroll
    for (int rg = 0; rg < 4; ++rg) {
      int row = mi * 16 + kg * 4 + rg;
#pragma unroll
      for (int ni = 0; ni < 2; ++ni)
        yo[(size_t)row * H_DIM + ni * 16 + ml] = f2bf_rn(acc[mi][ni][rg]);
    }
}

// ---------------- combine: out[t] = sum_k w[t,k] * yd[inv[t,k]] ----------------
__global__ void k_combine(const unsigned short* __restrict__ yd, const int* __restrict__ inv,
                          const float* __restrict__ wts, float* __restrict__ out) {
  const int t = blockIdx.x * 4 + (threadIdx.x >> 6);  // one wave per token
  const int lane = threadIdx.x & 63;
  const int i0 = 2 * t, i1 = 2 * t + 1;
  const int r0 = inv[i0], r1 = inv[i1];
  float o[8] = {0.f, 0.f, 0.f, 0.f, 0.f, 0.f, 0.f, 0.f};
  if (r0 >= 0) {
    float w = wts[i0];
    short8 y = *(const short8*)(yd + (size_t)r0 * H_DIM + lane * 8);
#pragma unroll
    for (int j = 0; j < 8; ++j) o[j] += w * bf2f((unsigned short)y[j]);
  }
  if (r1 >= 0) {
    float w = wts[i1];
    short8 y = *(const short8*)(yd + (size_t)r1 * H_DIM + lane * 8);
#pragma unroll
    for (int j = 0; j < 8; ++j) o[j] += w * bf2f((unsigned short)y[j]);
  }
  float4v v0 = {o[0], o[1], o[2], o[3]};
  float4v v1 = {o[4], o[5], o[6], o[7]};
  float4v* dst = (float4v*)(out + (size_t)t * H_DIM + lane * 8);
  dst[0] = v0;
  dst[1] = v1;
}

extern "C" void kernel_launch(void* const* d_in, const int* in_sizes, int n_in,
                              void* d_out, int out_size, void* d_ws, size_t ws_size,
                              hipStream_t stream) {
  const float* hs  = (const float*)d_in[0];  // [T,H]
  const int*   idx = (const int*)d_in[1];    // [T,K]
  const float* wts = (const float*)d_in[2];  // [T,K]
  const float* gup = (const float*)d_in[3];  // [E,2I,H]
  const float* dwn = (const float*)d_in[4];  // [E,H,I]
  float* out = (float*)d_out;                // [T,H]

  char* ws = (char*)d_ws;
  int* counts       = (int*)ws;                             // 128 B used
  int* inv          = (int*)(ws + 1024);                    // 32 KB
  int* slot_token   = (int*)(ws + 1024 + 32768);            // 64 KB
  unsigned short* xd  = (unsigned short*)(ws + 131072);     // 16 MB
  unsigned short* act = xd + (size_t)NROWS * H_DIM;         // 32 MB
  unsigned short* yd  = xd;  // xd dead after gemm1; alias (16 MB)

  hipMemsetAsync(counts, 0, E_NUM * sizeof(int), stream);
  k_route<<<NPAIR / 256, 256, 0, stream>>>(idx, counts, slot_token, inv);
  k_gather<<<NROWS / 4, 256, 0, stream>>>(hs, counts, slot_token, xd);
  dim3 g1(I_DIM / 64, NROWS / 64);   // 16 x 256 = 4096 blocks, ~2048 active
  k_gemm1<<<g1, 128, 0, stream>>>(xd, gup, counts, act);
  dim3 g2(H_DIM / 64, NROWS / 64);   // 8 x 256 = 2048 blocks, ~1024 active
  k_gemm2<<<g2, 128, 0, stream>>>(act, dwn, counts, yd);
  k_combine<<<T_TOK / 4, 256, 0, stream>>>(yd, inv, wts, out);
}